// Round 8
// baseline (322.595 us; speedup 1.0000x reference)
//
#include <hip/hip_runtime.h>

// MHSA. Inputs fp32, output fp32. B=4, T=2048, D=1024, H=16, hd=64.
// R8: attn S^T trick — compute S^T = K*Q^T (same LDS reads, swapped MFMA
// operands) so P^T enters PV as the B-operand via an in-register half-wave
// exchange (8x shfl_xor(32)) instead of the LDS round-trip. lsum is a
// per-lane scalar. Ps deleted; Qs reused for the O epilogue transpose.

typedef __attribute__((ext_vector_type(8))) short bf16x8;
typedef __attribute__((ext_vector_type(8))) unsigned short u16x8;
typedef __attribute__((ext_vector_type(4))) float f32x4;
typedef __attribute__((ext_vector_type(16))) float f32x16;

#define DEV static __device__ __forceinline__

DEV unsigned short f2b(float f) {  // RTNE f32 -> bf16
  union { float f; unsigned int i; } v; v.f = f;
  unsigned int x = v.i;
  return (unsigned short)((x + 0x7FFFu + ((x >> 16) & 1u)) >> 16);
}

DEV unsigned int f2b_pk(float lo, float hi) {  // pack two bf16 into a dword
#if defined(__has_builtin) && __has_builtin(__builtin_amdgcn_cvt_pk_bf16_f32)
  typedef __attribute__((ext_vector_type(2))) __bf16 bf2;
  bf2 p = __builtin_amdgcn_cvt_pk_bf16_f32(lo, hi);
  union { bf2 b; unsigned int u; } v; v.b = p; return v.u;
#else
  return (unsigned int)f2b(lo) | ((unsigned int)f2b(hi) << 16);
#endif
}

DEV f32x4 mfma16(bf16x8 a, bf16x8 b, f32x4 c) {
  return __builtin_amdgcn_mfma_f32_16x16x32_bf16(a, b, c, 0, 0, 0);
}
DEV f32x16 mfma32(bf16x8 a, bf16x8 b, f32x16 c) {
  return __builtin_amdgcn_mfma_f32_32x32x16_bf16(a, b, c, 0, 0, 0);
}

DEV void gl_lds16(const unsigned short* g, unsigned short* l) {
  __builtin_amdgcn_global_load_lds(
      (const __attribute__((address_space(1))) unsigned int*)g,
      (__attribute__((address_space(3))) unsigned int*)l, 16, 0, 0);
}

// ---------------------------------------------------------------- convert
__global__ __launch_bounds__(256) void f32_to_bf16(
    const float* __restrict__ in, unsigned short* __restrict__ out, int n4) {
  const int i = (blockIdx.x * 256 + threadIdx.x) * 4;
  if (i >= n4 * 4) return;
  const float4 v = *(const float4*)(in + i);
  ushort4 o;
  o.x = f2b(v.x); o.y = f2b(v.y); o.z = f2b(v.z); o.w = f2b(v.w);
  *(ushort4*)(out + i) = o;
}

// ---------------------------------------------------------------- transpose
__global__ __launch_bounds__(256) void transpose_f32_bf16(
    const float* __restrict__ in, unsigned short* __restrict__ out,
    int R, int C) {
  __shared__ float tile[32][33];
  const int tx = threadIdx.x & 31, ty = threadIdx.x >> 5;
  const int c0 = blockIdx.x * 32, r0 = blockIdx.y * 32;
#pragma unroll
  for (int i = 0; i < 32; i += 8)
    tile[ty + i][tx] = in[(size_t)(r0 + ty + i) * C + (c0 + tx)];
  __syncthreads();
#pragma unroll
  for (int i = 0; i < 32; i += 8)
    out[(size_t)(c0 + ty + i) * R + (r0 + tx)] = f2b(tile[tx][ty + i]);
}

// V [bh][t][d] -> Vt [bh][d][t]
__global__ __launch_bounds__(256) void vtrans(
    const unsigned short* __restrict__ in, unsigned short* __restrict__ out) {
  __shared__ __align__(16) unsigned short tile[64 * 72];
  const int tid = threadIdx.x;
  const int bh = blockIdx.y, t0 = blockIdx.x * 64;
  const unsigned short* src = in + (size_t)bh * 131072 + (size_t)t0 * 64;
  unsigned short* dst = out + (size_t)bh * 131072 + t0;
#pragma unroll
  for (int i = 0; i < 2; ++i) {
    const int c = tid + i * 256;
    u16x8 v = *(const u16x8*)(src + c * 8);
    *(u16x8*)&tile[(c >> 3) * 72 + (c & 7) * 8] = v;
  }
  __syncthreads();
#pragma unroll
  for (int i = 0; i < 2; ++i) {
    const int c = tid + i * 256;
    const int d = c >> 3, t8 = (c & 7) * 8;
    u16x8 o;
#pragma unroll
    for (int j = 0; j < 8; ++j) o[j] = tile[(t8 + j) * 72 + d];
    *(u16x8*)(dst + (size_t)d * 2048 + t8) = o;
  }
}

// ---------------------------------------------------------------- GEMM
#define QSCALE 0.18033688f  // 0.125 * log2(e)
template <int MODE>
__global__ __launch_bounds__(256, 2) void gemm_bt(
    const unsigned short* __restrict__ A, const unsigned short* __restrict__ Bt,
    const float* __restrict__ bias, void* __restrict__ out_v,
    int M, int N, int K) {
  __shared__ __align__(16) unsigned short As[128 * 32];
  __shared__ __align__(16) unsigned short Bs[128 * 32];
  const int tid = threadIdx.x;
  const int w = tid >> 6, l = tid & 63, g = l >> 4, ln = l & 15;
  const int m0 = blockIdx.y * 128, n0 = blockIdx.x * 128;
  const int wm = (w & 1) * 64, wn = (w >> 1) * 64;

  f32x4 acc[4][4];
#pragma unroll
  for (int i = 0; i < 4; ++i)
#pragma unroll
    for (int j = 0; j < 4; ++j) acc[i][j] = (f32x4){0.f, 0.f, 0.f, 0.f};

  const unsigned short* Ab = A + (size_t)m0 * K;
  const unsigned short* Bb = Bt + (size_t)n0 * K;
  const int c0 = tid, c1 = tid + 256;
  const int ar0 = c0 >> 2, ak0 = (c0 & 3) * 8;
  const int ar1 = c1 >> 2, ak1 = (c1 & 3) * 8;

  for (int k0 = 0; k0 < K; k0 += 32) {
    gl_lds16(Ab + (size_t)ar0 * K + k0 + ak0, &As[c0 * 8]);
    gl_lds16(Ab + (size_t)ar1 * K + k0 + ak1, &As[c1 * 8]);
    gl_lds16(Bb + (size_t)ar0 * K + k0 + ak0, &Bs[c0 * 8]);
    gl_lds16(Bb + (size_t)ar1 * K + k0 + ak1, &Bs[c1 * 8]);
    __syncthreads();
    bf16x8 af[4], bf[4];
#pragma unroll
    for (int mi = 0; mi < 4; ++mi)
      af[mi] = *(const bf16x8*)&As[(wm + mi * 16 + ln) * 32 + g * 8];
#pragma unroll
    for (int ni = 0; ni < 4; ++ni)
      bf[ni] = *(const bf16x8*)&Bs[(wn + ni * 16 + ln) * 32 + g * 8];
#pragma unroll
    for (int mi = 0; mi < 4; ++mi)
#pragma unroll
      for (int ni = 0; ni < 4; ++ni)
        acc[mi][ni] = mfma16(af[mi], bf[ni], acc[mi][ni]);
    __syncthreads();
  }

#pragma unroll
  for (int mi = 0; mi < 4; ++mi) {
#pragma unroll
    for (int ni = 0; ni < 4; ++ni) {
      const int row0 = m0 + wm + mi * 16 + 4 * g;
      const int col = n0 + wn + ni * 16 + ln;
      const float bv = bias[col];
#pragma unroll
      for (int r = 0; r < 4; ++r) {
        float v = acc[mi][ni][r] + bv;
        const int row = row0 + r;
        if (MODE == 0) {
          const int which = col >> 10;           // 0=Q 1=K 2=V
          const int h = (col >> 6) & 15;
          const int dd = col & 63;
          const int b = row >> 11, t = row & 2047;
          unsigned short* dst = (unsigned short*)out_v + (size_t)which * 8388608u;
          if (which == 0) v *= QSCALE;
          dst[(((size_t)(b * 16 + h)) * 2048 + t) * 64 + dd] = f2b(v);
        } else {
          ((float*)out_v)[(size_t)row * N + col] = v;
        }
      }
    }
  }
}

// ---------------------------------------------------------------- attention
// Block: (bh, 128-q tile); wave w owns q rows [32w,32w+32), q = lane&31.
// S^T = K*Q^T (mfma32, A=K frag, B=Q frag). C/D: col=l&31(=q),
// row=(r&3)+8*(r>>2)+4*lh (=key). exp2 in place, per-lane scalar lsum.
// P^T re-enters PV (O^T = V^T * P^T) as B-operand: dword pairs packed and
// exchanged across half-waves with shfl_xor(32). O^T transposed via LDS
// (reusing Qs) for coalesced Y writes.
__global__ __launch_bounds__(256, 4) void attn(
    const unsigned short* __restrict__ Q, const unsigned short* __restrict__ K,
    const unsigned short* __restrict__ Vtg, unsigned short* __restrict__ Y) {
  __shared__ __align__(16) unsigned short Qs[128 * 72];  // then O tile
  __shared__ __align__(16) unsigned short Ks[64 * 72];   // [key][d]
  __shared__ __align__(16) unsigned short Vt[64 * 72];   // [d][key]

  const int tid = threadIdx.x;
  const int w = tid >> 6, l = tid & 63;
  const int l32 = l & 31, lh = l >> 5;
  const int bh = blockIdx.y;
  const int q0 = blockIdx.x * 128;

  const unsigned short* Qb = Q + (size_t)bh * 131072;    // [t][d]
  const unsigned short* Kb = K + (size_t)bh * 131072;    // [t][d]
  const unsigned short* Vb = Vtg + (size_t)bh * 131072;  // [d][t]

  // stage Q: 128x64 -> stride-72 rows
#pragma unroll
  for (int i = 0; i < 4; ++i) {
    const int c = tid + i * 256;
    u16x8 v = *(const u16x8*)(Qb + (size_t)q0 * 64 + c * 8);
    *(u16x8*)&Qs[(c >> 3) * 72 + (c & 7) * 8] = v;
  }
  __syncthreads();
  bf16x8 aq[4];  // B-frag of S^T: n=q=l32, k=d
#pragma unroll
  for (int kb = 0; kb < 4; ++kb)
    aq[kb] = *(const bf16x8*)&Qs[(w * 32 + l32) * 72 + kb * 16 + lh * 8];

  f32x16 o[2];
#pragma unroll
  for (int db = 0; db < 2; ++db)
#pragma unroll
    for (int r = 0; r < 16; ++r) o[db][r] = 0.f;
  float ls0 = 0.f, ls1 = 0.f, ls2 = 0.f, ls3 = 0.f;  // lsum partials

  for (int kt = 0; kt < 32; ++kt) {
#pragma unroll
    for (int i = 0; i < 2; ++i) {
      const int c = tid + i * 256;
      const int row = c >> 3, cc = (c & 7) * 8;
      u16x8 kv = *(const u16x8*)(Kb + (size_t)kt * 4096 + c * 8);
      u16x8 vv = *(const u16x8*)(Vb + (size_t)row * 2048 + kt * 64 + cc);
      *(u16x8*)&Ks[row * 72 + cc] = kv;
      *(u16x8*)&Vt[row * 72 + cc] = vv;
    }
    __syncthreads();

    // S^T: two key m-blocks; lane holds keys over regs for q=l32
    f32x16 st[2];
#pragma unroll
    for (int mb = 0; mb < 2; ++mb) {
#pragma unroll
      for (int r = 0; r < 16; ++r) st[mb][r] = 0.f;
#pragma unroll
      for (int kb = 0; kb < 4; ++kb) {
        bf16x8 ak = *(const bf16x8*)&Ks[(mb * 32 + l32) * 72 + kb * 16 + lh * 8];
        st[mb] = mfma32(ak, aq[kb], st[mb]);
      }
    }

    // exp2 + lsum partials + pack pairs: pk[mb][j] = keys(regs 2j,2j+1)
    unsigned int pk[2][8];
#pragma unroll
    for (int mb = 0; mb < 2; ++mb)
#pragma unroll
      for (int j = 0; j < 8; ++j) {
        const float pa = exp2f(st[mb][2 * j]);
        const float pb = exp2f(st[mb][2 * j + 1]);
        ls0 += pa; ls1 += pb;
        pk[mb][j] = f2b_pk(pa, pb);
      }

    // half-wave exchange: half h sends pk[j] the other half needs
    unsigned int rcv[2][4];
#pragma unroll
    for (int mb = 0; mb < 2; ++mb) {
      static const int snd_lo[4] = {2, 3, 6, 7};   // sent by lh=0
      static const int snd_hi[4] = {0, 1, 4, 5};   // sent by lh=1
#pragma unroll
      for (int i = 0; i < 4; ++i) {
        const unsigned int s = lh ? pk[mb][snd_hi[i]] : pk[mb][snd_lo[i]];
        rcv[mb][i] = (unsigned int)__shfl_xor((int)s, 32);
      }
    }

    // PV: O^T += V^T * P^T  (A = V^T frag, B = P^T frag assembled)
#pragma unroll
    for (int ks = 0; ks < 4; ++ks) {
      const int mb = ks >> 1, kl = ks & 1;
      union { unsigned int d[4]; bf16x8 v; } bp;
      bp.d[0] = lh ? rcv[mb][2 * kl + 0] : pk[mb][4 * kl + 0];
      bp.d[1] = lh ? rcv[mb][2 * kl + 1] : pk[mb][4 * kl + 1];
      bp.d[2] = lh ? pk[mb][4 * kl + 2] : rcv[mb][2 * kl + 0];
      bp.d[3] = lh ? pk[mb][4 * kl + 3] : rcv[mb][2 * kl + 1];
#pragma unroll
      for (int db = 0; db < 2; ++db) {
        bf16x8 av = *(const bf16x8*)&Vt[(db * 32 + l32) * 72 + ks * 16 + lh * 8];
        o[db] = mfma32(av, bp.v, o[db]);
      }
    }
    __syncthreads();
  }

  // finish lsum: combine partials + other half-wave (q=l32 both halves)
  float lsum = (ls0 + ls1) + (ls2 + ls3);
  lsum += __shfl_xor(lsum, 32);
  const float iv = 1.f / lsum;

  // O^T regs -> LDS [q][d] (reuse Qs), then coalesced Y writes
  unsigned short* Os = Qs;
#pragma unroll
  for (int db = 0; db < 2; ++db)
#pragma unroll
    for (int rp = 0; rp < 8; ++rp) {   // reg pairs (2rp, 2rp+1) -> d, d+1
      const int r = 2 * rp;
      const int d = db * 32 + (r & 3) + 8 * (r >> 2) + 4 * lh;
      const unsigned int pv = f2b_pk(o[db][r] * iv, o[db][r + 1] * iv);
      *(unsigned int*)&Os[(w * 32 + l32) * 72 + d] = pv;
    }
  __syncthreads();
  const int b = bh >> 4, h = bh & 15;
#pragma unroll
  for (int i = 0; i < 4; ++i) {
    const int c = tid + i * 256;
    const int q = c >> 3, col = (c & 7) * 8;
    u16x8 v = *(const u16x8*)&Os[q * 72 + col];
    *(u16x8*)(Y + ((size_t)(b * 2048 + q0 + q)) * 1024 + h * 64 + col) = v;
  }
}

// ---------------------------------------------------------------- launch
extern "C" void kernel_launch(void* const* d_in, const int* in_sizes, int n_in,
                              void* d_out, int out_size, void* d_ws, size_t ws_size,
                              hipStream_t stream) {
  const float* x     = (const float*)d_in[0];
  const float* Wqkv  = (const float*)d_in[1];
  const float* bqkv  = (const float*)d_in[2];
  const float* Wproj = (const float*)d_in[3];
  const float* bproj = (const float*)d_in[4];
  float* out = (float*)d_out;
  unsigned short* ws = (unsigned short*)d_ws;

  unsigned short* xbf    = ws;
  unsigned short* Yw     = xbf;  // alias: x dead after gemm<0>
  unsigned short* WqkvT  = xbf + 8388608;
  unsigned short* WprojT = WqkvT + 3072 * 1024;
  unsigned short* Qw     = WprojT + 1024 * 1024;
  unsigned short* Kw     = Qw + 8388608;
  unsigned short* Vw     = Kw + 8388608;   // [b,h,t,d]
  unsigned short* Vtw    = Vw + 8388608;   // [b,h,d,t]

  f32_to_bf16<<<8192, 256, 0, stream>>>(x, xbf, 2097152);
  transpose_f32_bf16<<<dim3(96, 32), 256, 0, stream>>>(Wqkv, WqkvT, 1024, 3072);
  transpose_f32_bf16<<<dim3(32, 32), 256, 0, stream>>>(Wproj, WprojT, 1024, 1024);
  gemm_bt<0><<<dim3(24, 64), 256, 0, stream>>>(xbf, WqkvT, bqkv, Qw, 8192, 3072, 1024);
  vtrans<<<dim3(32, 64), 256, 0, stream>>>(Vw, Vtw);
  attn<<<dim3(16, 64), 256, 0, stream>>>(Qw, Kw, Vtw, Yw);
  gemm_bt<1><<<dim3(8, 64), 256, 0, stream>>>(Yw, WprojT, bproj, out, 8192, 1024, 1024);
}